// Round 6
// baseline (283.056 us; speedup 1.0000x reference)
//
#include <hip/hip_runtime.h>
#include <math.h>

// Problem: images [64,256,256] f32 -> patches [16384][256] f32 (identity perm)
//          tokens [16384] = argmin_v ||patch - vocab[v]||^2, vocab [4096][256] f32
#define PS      16
#define D       256
#define V       4096
#define M       16384
#define NSPLIT  8               // V / 512 column splits (gemm grid.y)
#define PAIR_CAP 2097152
// Scores packed as u32 keys: q = (u32)((s + 1024) * 512)  (20 bits), key =
// (q << 12) | col. min() on keys = argmin with lowest-index tie-break.
// fp16 score-diff error sigma ~3e-2; QMARGIN 130 quanta (=0.254) is ~8 sigma
// incl. trunc slack -> P(true-argmin excluded) ~1e-12 per patch. Flagged
// (~4%) get exact fp64 on a candidate set provably containing the argmin.
#define QMARGIN 130

typedef _Float16 half8 __attribute__((ext_vector_type(8)));
typedef _Float16 half4 __attribute__((ext_vector_type(4)));
typedef float    f32x4 __attribute__((ext_vector_type(4)));

__device__ __forceinline__ void gload_lds16(const void* g, void* l) {
  __builtin_amdgcn_global_load_lds(
      (const __attribute__((address_space(1))) unsigned int*)g,
      (__attribute__((address_space(3))) unsigned int*)l, 16, 0, 0);
}

// ---------------------------------------------------------------------------
// Kernel 1: patchify (float4) + fp16 copy; block 0 also zeros pair counter.
// ---------------------------------------------------------------------------
__global__ __launch_bounds__(256) void patchify_half_kernel(
    const float* __restrict__ img, float* __restrict__ outp,
    _Float16* __restrict__ Ah, int* __restrict__ paircount) {
  if (blockIdx.x == 0 && threadIdx.x == 0) *paircount = 0;
  const int t  = blockIdx.x * 256 + threadIdx.x;   // M*D/4 threads
  const int o4 = t << 2;
  const int b   = o4 >> 16;
  const int rem = o4 & 65535;
  const int n   = rem >> 8;
  const int d   = rem & 255;
  const int py = n >> 4, px = n & 15, i = d >> 4, j = d & 15;
  const float4 v = *(const float4*)(img + (b << 16) + ((py * PS + i) << 8) + px * PS + j);
  *(float4*)(outp + o4) = v;
  half4 h = { (_Float16)v.x, (_Float16)v.y, (_Float16)v.z, (_Float16)v.w };
  *(half4*)(Ah + o4) = h;
}

// ---------------------------------------------------------------------------
// Kernel 2: vocab -> fp16 copy + v2[v] = sum_d vocab[v][d]^2 (one wave / row)
// ---------------------------------------------------------------------------
__global__ __launch_bounds__(256) void vocab_half_v2_kernel(
    const float* __restrict__ vocab, _Float16* __restrict__ Vh,
    float* __restrict__ v2) {
  const int gtid = blockIdx.x * 256 + threadIdx.x;
  const int row  = gtid >> 6;
  const int lane = gtid & 63;
  const float4 v = *(const float4*)(vocab + (size_t)row * D + (lane << 2));
  half4 h = { (_Float16)v.x, (_Float16)v.y, (_Float16)v.z, (_Float16)v.w };
  *(half4*)(Vh + (size_t)row * D + (lane << 2)) = h;
  float s = v.x * v.x + v.y * v.y + v.z * v.z + v.w * v.w;
  #pragma unroll
  for (int off = 32; off > 0; off >>= 1) s += __shfl_down(s, off);
  if (lane == 0) v2[row] = s;
}

// ---------------------------------------------------------------------------
// Kernel 3: fp16 MFMA score GEMM, spill-free / barrier-free K-loop.
// Block = 64 rows x 512 cols. A tile (64 x 256) LDS-resident, staged once
// (XOR-swizzled granules -> balanced ds_read_b128). B fragments loaded
// directly global->VGPR (contiguous 16B per lane, L2-resident), software-
// pipelined one kt ahead. Waves 1x4: wave w covers cols [vt*128 + w*32).
// Per-row running top-2 as packed u32 keys; partials [NSPLIT][M].
// ---------------------------------------------------------------------------
__global__ __launch_bounds__(256, 3) void gemm_score_kernel(
    const _Float16* __restrict__ Ah,   // [M][256]
    const _Float16* __restrict__ Vh,   // [V][256]
    const float* __restrict__ v2,
    unsigned* __restrict__ pk1, unsigned* __restrict__ pk2) {
  __shared__ __align__(16) _Float16 Af[8 * 64 * 32];  // [kt][row][32 halves]
  __shared__ unsigned eK1[64][4];
  __shared__ unsigned eK2[64][4];

  const int tid  = threadIdx.x;
  const int lane = tid & 63;
  const int wid  = tid >> 6;
  const int row0 = blockIdx.x * 64;
  const int colB = blockIdx.y * 512;

  // ---- stage whole A tile once (8 gloads/wave, one barrier) ----
  // lane -> row wid*16 + (lane>>2), LDS granule (lane&3); fetch global
  // granule (lane&3)^((srow>>1)&3) so frag reads are bank-balanced.
  {
    const int srow = lane >> 2;
    const int sg   = ((lane & 3) ^ ((srow >> 1) & 3)) << 3;   // halves
    const _Float16* Ag = Ah + (size_t)(row0 + wid * 16 + srow) * D + sg;
    _Float16* Al = Af + wid * 16 * 32;
    #pragma unroll
    for (int kt = 0; kt < 8; ++kt)
      gload_lds16(Ag + kt * 32, Al + kt * 64 * 32);
  }
  __syncthreads();

  const int cl = lane & 15;           // fragment row/col within 16
  const int q  = lane >> 4;           // quad: k-chunk selector
  const int fg = (q ^ ((cl >> 1) & 3)) << 3;           // swizzled granule
  const _Float16* Ab = Af + cl * 32 + fg;              // + kt*2048 + i*512

  unsigned kk1[16], kk2[16];
  #pragma unroll
  for (int p = 0; p < 16; ++p) { kk1[p] = 0xFFFFFFFFu; kk2[p] = 0xFFFFFFFFu; }

  for (int vt = 0; vt < 4; ++vt) {
    const int c0 = colB + vt * 128 + wid * 32 + cl;    // j=0 col for this lane
    const int c1 = c0 + 16;                            // j=1 col
    const _Float16* B0 = Vh + (size_t)c0 * D + q * 8;
    const _Float16* B1 = Vh + (size_t)c1 * D + q * 8;

    f32x4 acc[4][2];
    #pragma unroll
    for (int i = 0; i < 4; ++i) {
      acc[i][0] = (f32x4){0.f, 0.f, 0.f, 0.f};
      acc[i][1] = (f32x4){0.f, 0.f, 0.f, 0.f};
    }

    half8 b0n = *(const half8*)(B0);
    half8 b1n = *(const half8*)(B1);
    #pragma unroll
    for (int kt = 0; kt < 8; ++kt) {
      const half8 b0 = b0n, b1 = b1n;
      if (kt < 7) {                    // prefetch next kt (compile-time guard)
        b0n = *(const half8*)(B0 + (kt + 1) * 32);
        b1n = *(const half8*)(B1 + (kt + 1) * 32);
      }
      half8 af[4];
      #pragma unroll
      for (int i = 0; i < 4; ++i)
        af[i] = *(const half8*)(Ab + kt * 2048 + i * 512);
      #pragma unroll
      for (int i = 0; i < 4; ++i) {
        acc[i][0] = __builtin_amdgcn_mfma_f32_16x16x32_f16(af[i], b0, acc[i][0], 0, 0, 0);
        acc[i][1] = __builtin_amdgcn_mfma_f32_16x16x32_f16(af[i], b1, acc[i][1], 0, 0, 0);
      }
    }

    // fold this 128-col tile into the running packed top-2.
    // C/D layout: col=lane&15, row=quad*4+reg (m89/m91-verified).
    // key_f = (score+1024)*512 = (v2+1024)*512 - 1024*acc
    const float C0 = fmaf(v2[c0], 512.0f, 524288.0f);
    const float C1 = fmaf(v2[c1], 512.0f, 524288.0f);
    #pragma unroll
    for (int i = 0; i < 4; ++i)
      #pragma unroll
      for (int r = 0; r < 4; ++r) {
        const int p = i * 4 + r;
        const unsigned k0 = ((unsigned)fmaf(-1024.0f, acc[i][0][r], C0) << 12) | (unsigned)c0;
        const unsigned k1 = ((unsigned)fmaf(-1024.0f, acc[i][1][r], C1) << 12) | (unsigned)c1;
        const unsigned ka = min(k0, k1), kb = max(k0, k1);
        kk2[p] = min(min(kk2[p], kb), max(kk1[p], ka));
        kk1[p] = min(kk1[p], ka);
      }
  }

  // butterfly top-2 merge across the 16 col-holder lanes (within quad group)
  #pragma unroll
  for (int p = 0; p < 16; ++p) {
    unsigned k1 = kk1[p], k2 = kk2[p];
    #pragma unroll
    for (int mask = 1; mask <= 8; mask <<= 1) {
      const unsigned o1 = (unsigned)__shfl_xor((int)k1, mask);
      const unsigned o2 = (unsigned)__shfl_xor((int)k2, mask);
      k2 = min(min(k2, o2), max(k1, o1));
      k1 = min(k1, o1);
    }
    if (cl == 0) {
      const int rl = (p >> 2) * 16 + q * 4 + (p & 3);
      eK1[rl][wid] = k1; eK2[rl][wid] = k2;
    }
  }
  __syncthreads();
  if (tid < 64) {
    unsigned K1 = 0xFFFFFFFFu, K2 = 0xFFFFFFFFu;
    #pragma unroll
    for (int w = 0; w < 4; ++w) {
      const unsigned b1 = eK1[tid][w], b2 = eK2[tid][w];
      K2 = min(min(K2, b2), max(K1, b1));
      K1 = min(K1, b1);
    }
    pk1[(size_t)blockIdx.y * M + row0 + tid] = K1;
    pk2[(size_t)blockIdx.y * M + row0 + tid] = K2;
  }
}

// ---------------------------------------------------------------------------
// Kernel 4: merge NSPLIT partials -> token; flagged patches emit fp64-rescore
// candidate pairs inline (heavy split -> all 512 rows; light -> its winner).
// Also inits minkey for the refine pass.
// ---------------------------------------------------------------------------
__global__ __launch_bounds__(256) void reduce_gather_kernel(
    const unsigned* __restrict__ pk1, const unsigned* __restrict__ pk2,
    float* __restrict__ tok, unsigned long long* __restrict__ minkey,
    unsigned* __restrict__ pairs, int* __restrict__ paircount) {
  const int m = blockIdx.x * 256 + threadIdx.x;
  unsigned b1s[NSPLIT], b2s[NSPLIT];
  unsigned K1 = 0xFFFFFFFFu, K2 = 0xFFFFFFFFu;
  #pragma unroll
  for (int s = 0; s < NSPLIT; ++s) {
    const unsigned b1 = pk1[(size_t)s * M + m];
    const unsigned b2 = pk2[(size_t)s * M + m];
    b1s[s] = b1; b2s[s] = b2;
    K2 = min(min(K2, b2), max(K1, b1));
    K1 = min(K1, b1);
  }
  tok[m] = (float)(K1 & 4095u);
  minkey[m] = 0xFFFFFFFFFFFFFFFFull;
  if ((int)(K2 >> 12) - (int)(K1 >> 12) <= QMARGIN) {
    const int th = (int)(K1 >> 12) + QMARGIN;
    int cnt = 0;
    #pragma unroll
    for (int s = 0; s < NSPLIT; ++s)
      cnt += ((int)(b2s[s] >> 12) <= th) ? 512
           : (((int)(b1s[s] >> 12) <= th) ? 1 : 0);
    int base = atomicAdd(paircount, cnt);
    if (base + cnt <= PAIR_CAP) {
      const unsigned mh = (unsigned)m << 12;
      #pragma unroll
      for (int s = 0; s < NSPLIT; ++s) {
        if ((int)(b2s[s] >> 12) <= th) {
          for (int r = 0; r < 512; ++r) pairs[base + r] = mh | (unsigned)(s * 512 + r);
          base += 512;
        } else if ((int)(b1s[s] >> 12) <= th) {
          pairs[base++] = mh | (b1s[s] & 4095u);
        }
      }
    }
  }
}

// ---------------------------------------------------------------------------
// Kernel 5: exact fp64 rescore, one wave per pair, single pass.
// key = (bits(d2) & ~0xFFF) | row: atomicMin = argmin with low-index
// tie-break; 12 dropped mantissa bits = ~1e-9 abs tolerance (safe).
// ---------------------------------------------------------------------------
__global__ __launch_bounds__(256) void refine_score(
    const float* __restrict__ patches, const float* __restrict__ vocab,
    const unsigned* __restrict__ pairs, const int* __restrict__ paircount,
    unsigned long long* __restrict__ minkey) {
  const int lane = threadIdx.x & 63;
  const int gw = (blockIdx.x * 256 + threadIdx.x) >> 6;
  const int nw = (gridDim.x * 256) >> 6;
  int np = *paircount;
  if (np > PAIR_CAP) np = PAIR_CAP;
  for (int i = gw; i < np; i += nw) {
    const unsigned pr = pairs[i];
    const int m = pr >> 12, row = pr & 4095;
    const float4 pv = *(const float4*)(patches + (size_t)m * D + (lane << 2));
    const float4 vv = *(const float4*)(vocab + (size_t)row * D + (lane << 2));
    double acc = 0.0, df;
    df = (double)pv.x - (double)vv.x; acc = fma(df, df, acc);
    df = (double)pv.y - (double)vv.y; acc = fma(df, df, acc);
    df = (double)pv.z - (double)vv.z; acc = fma(df, df, acc);
    df = (double)pv.w - (double)vv.w; acc = fma(df, df, acc);
    #pragma unroll
    for (int off = 32; off > 0; off >>= 1) acc += __shfl_down(acc, off);
    if (lane == 0) {
      const unsigned long long key =
          ((unsigned long long)__double_as_longlong(acc) & ~0xFFFull) | (unsigned)row;
      atomicMin(&minkey[m], key);
    }
  }
}

// ---------------------------------------------------------------------------
// Kernel 6: write refined tokens (grid-stride over pairs; redundant same-value
// writes per flagged patch are benign).
// ---------------------------------------------------------------------------
__global__ __launch_bounds__(256) void refine_final(
    const unsigned* __restrict__ pairs, const int* __restrict__ paircount,
    const unsigned long long* __restrict__ minkey, float* __restrict__ tok) {
  int np = *paircount;
  if (np > PAIR_CAP) np = PAIR_CAP;
  for (int i = blockIdx.x * 256 + threadIdx.x; i < np; i += gridDim.x * 256) {
    const int m = pairs[i] >> 12;
    tok[m] = (float)(unsigned)(minkey[m] & 4095ull);
  }
}

// ---------------------------------------------------------------------------
extern "C" void kernel_launch(void* const* d_in, const int* in_sizes, int n_in,
                              void* d_out, int out_size, void* d_ws, size_t ws_size,
                              hipStream_t stream) {
  const float* images = (const float*)d_in[0];   // [64,256,256]
  const float* vocab  = (const float*)d_in[1];   // [4096,256]
  float* out     = (float*)d_out;
  float* patches = out;            // M*D floats
  float* tokens  = out + (size_t)M * D;

  // workspace layout (bytes):
  // Ah 8MB | Vh 2MB | v2 16KB | pk1 512KB | pk2 512KB | minkey 128KB |
  // paircount 64B | pairs 8MB   (~19.1 MB)
  char* ws = (char*)d_ws;
  _Float16* Ah       = (_Float16*)(ws);
  _Float16* Vh       = (_Float16*)(ws + 8388608);
  float*    v2       = (float*)   (ws + 10485760);
  unsigned* pk1      = (unsigned*)(ws + 10502144);
  unsigned* pk2      = (unsigned*)(ws + 11026432);
  unsigned long long* minkey = (unsigned long long*)(ws + 11550720);
  int*      paircount= (int*)     (ws + 11681792);
  unsigned* pairs    = (unsigned*)(ws + 11681856);

  patchify_half_kernel<<<(M * D / 4) / 256, 256, 0, stream>>>(images, patches, Ah,
                                                              paircount);
  vocab_half_v2_kernel<<<(V * 64) / 256, 256, 0, stream>>>(vocab, Vh, v2);
  gemm_score_kernel<<<dim3(M / 64, NSPLIT), 256, 0, stream>>>(Ah, Vh, v2, pk1, pk2);
  reduce_gather_kernel<<<M / 256, 256, 0, stream>>>(pk1, pk2, tokens, minkey,
                                                    pairs, paircount);
  refine_score<<<512, 256, 0, stream>>>(patches, vocab, pairs, paircount, minkey);
  refine_final<<<64, 256, 0, stream>>>(pairs, paircount, minkey, tokens);
}

// Round 7
// 177.265 us; speedup vs baseline: 1.5968x; 1.5968x over previous
//
#include <hip/hip_runtime.h>
#include <math.h>

// Problem: images [64,256,256] f32 -> patches [16384][256] f32 (identity perm)
//          tokens [16384] = argmin_v ||patch - vocab[v]||^2, vocab [4096][256] f32
#define PS      16
#define D       256
#define V       4096
#define M       16384
#define NSPLIT  32              // V / 128 column splits
#define PAIR_CAP 1048576
// Scores packed as u32 keys: q = (u32)((s + 1024) * 512)  (20 bits), key =
// (q << 12) | col. min() on keys = argmin with lowest-index tie-break.
// fp16 score-diff error sigma ~3e-2; QMARGIN 130 quanta (=0.254) is ~8 sigma
// incl. trunc slack -> P(true-argmin excluded) negligible. Flagged (~4%)
// get exact fp64 on a candidate set provably containing the argmin.
#define QMARGIN 130

typedef _Float16 half8 __attribute__((ext_vector_type(8)));
typedef _Float16 half4 __attribute__((ext_vector_type(4)));
typedef float    f32x4 __attribute__((ext_vector_type(4)));

__device__ __forceinline__ void gload_lds16(const void* g, void* l) {
  __builtin_amdgcn_global_load_lds(
      (const __attribute__((address_space(1))) unsigned int*)g,
      (__attribute__((address_space(3))) unsigned int*)l, 16, 0, 0);
}

// ---------------------------------------------------------------------------
// Kernel 1: patchify (float4) + fp16 copy; block 0 also zeros pair counter.
// ---------------------------------------------------------------------------
__global__ __launch_bounds__(256) void patchify_half_kernel(
    const float* __restrict__ img, float* __restrict__ outp,
    _Float16* __restrict__ Ah, int* __restrict__ paircount) {
  if (blockIdx.x == 0 && threadIdx.x == 0) *paircount = 0;
  const int t  = blockIdx.x * 256 + threadIdx.x;   // M*D/4 threads
  const int o4 = t << 2;
  const int b   = o4 >> 16;
  const int rem = o4 & 65535;
  const int n   = rem >> 8;
  const int d   = rem & 255;
  const int py = n >> 4, px = n & 15, i = d >> 4, j = d & 15;
  const float4 v = *(const float4*)(img + (b << 16) + ((py * PS + i) << 8) + px * PS + j);
  *(float4*)(outp + o4) = v;
  half4 h = { (_Float16)v.x, (_Float16)v.y, (_Float16)v.z, (_Float16)v.w };
  *(half4*)(Ah + o4) = h;
}

// ---------------------------------------------------------------------------
// Kernel 2: vocab -> fp16 copy + v2[v] = sum_d vocab[v][d]^2 (one wave / row)
// ---------------------------------------------------------------------------
__global__ __launch_bounds__(256) void vocab_half_v2_kernel(
    const float* __restrict__ vocab, _Float16* __restrict__ Vh,
    float* __restrict__ v2) {
  const int gtid = blockIdx.x * 256 + threadIdx.x;
  const int row  = gtid >> 6;
  const int lane = gtid & 63;
  const float4 v = *(const float4*)(vocab + (size_t)row * D + (lane << 2));
  half4 h = { (_Float16)v.x, (_Float16)v.y, (_Float16)v.z, (_Float16)v.w };
  *(half4*)(Vh + (size_t)row * D + (lane << 2)) = h;
  float s = v.x * v.x + v.y * v.y + v.z * v.z + v.w * v.w;
  #pragma unroll
  for (int off = 32; off > 0; off >>= 1) s += __shfl_down(s, off);
  if (lane == 0) v2[row] = s;
}

// ---------------------------------------------------------------------------
// Kernel 3: fp16 MFMA score GEMM, spill-free by construction.
// Block = 64 rows x 128 cols; grid (V/128, M/64) col-fast (A-tile L2-warm).
// A tile (64x256, 32KB) LDS-resident, staged once via swizzled
// global_load_lds, ONE barrier. B fragments direct global->VGPR (16B/lane,
// Vh 2MB = L2-resident). kt loop NOT unrolled (#pragma unroll 1) -- R6's
// spill came from full-unroll hoisting all loads. Top-2 only in epilogue:
// each wave owns 32 cols -> per p exactly 2 scores, one butterfly per block.
// ---------------------------------------------------------------------------
__global__ __launch_bounds__(256, 3) void gemm_score_kernel(
    const _Float16* __restrict__ Ah,   // [M][256]
    const _Float16* __restrict__ Vh,   // [V][256]
    const float* __restrict__ v2,
    unsigned* __restrict__ pk1, unsigned* __restrict__ pk2) {
  __shared__ __align__(16) _Float16 Af[8 * 64 * 32];  // [kt][row][32] = 32 KB
  __shared__ unsigned eK1[64][4];
  __shared__ unsigned eK2[64][4];

  const int tid  = threadIdx.x;
  const int lane = tid & 63;
  const int wid  = tid >> 6;
  const int cb   = blockIdx.x;        // col block 0..31 (fast dim)
  const int row0 = blockIdx.y * 64;
  const int col0 = cb * 128 + wid * 32;   // this wave's 32 cols

  // ---- stage A tile once (8 gloads/wave, one barrier) ----
  // global addr carries the XOR swizzle; HW writes LDS at base + lane*16,
  // so LDS granule p of row r holds global granule p ^ ((r>>1)&3).
  {
    const int srow = lane >> 2;
    const int sg   = ((lane & 3) ^ ((srow >> 1) & 3)) << 3;   // halves
    const _Float16* Ag = Ah + (size_t)(row0 + wid * 16 + srow) * D + sg;
    _Float16* Al = Af + wid * 16 * 32;
    #pragma unroll
    for (int kt = 0; kt < 8; ++kt)
      gload_lds16(Ag + kt * 32, Al + kt * 64 * 32);
  }
  __syncthreads();

  const int cl = lane & 15;           // fragment row/col within 16
  const int q  = lane >> 4;           // quad: k-chunk selector
  const int fg = (q ^ ((cl >> 1) & 3)) << 3;           // de-swizzle granule
  const _Float16* Ab = Af + cl * 32 + fg;

  const int c0 = col0 + cl;           // j=0 col
  const int c1 = c0 + 16;             // j=1 col
  const _Float16* B0 = Vh + (size_t)c0 * D + q * 8;
  const _Float16* B1 = Vh + (size_t)c1 * D + q * 8;

  f32x4 acc[4][2];
  #pragma unroll
  for (int i = 0; i < 4; ++i) {
    acc[i][0] = (f32x4){0.f, 0.f, 0.f, 0.f};
    acc[i][1] = (f32x4){0.f, 0.f, 0.f, 0.f};
  }

  #pragma unroll 1                    // keep live set bounded (R6 lesson)
  for (int kt = 0; kt < 8; ++kt) {
    const half8 b0 = *(const half8*)(B0 + kt * 32);
    const half8 b1 = *(const half8*)(B1 + kt * 32);
    half8 af[4];
    #pragma unroll
    for (int i = 0; i < 4; ++i)
      af[i] = *(const half8*)(Ab + kt * 2048 + i * 512);
    #pragma unroll
    for (int i = 0; i < 4; ++i) {
      acc[i][0] = __builtin_amdgcn_mfma_f32_16x16x32_f16(af[i], b0, acc[i][0], 0, 0, 0);
      acc[i][1] = __builtin_amdgcn_mfma_f32_16x16x32_f16(af[i], b1, acc[i][1], 0, 0, 0);
    }
  }

  // Epilogue. C/D layout: col=lane&15, row=quad*4+reg (m89/m91-verified).
  // key_f = (score+1024)*512 = (v2+1024)*512 - 1024*acc
  const float C0 = fmaf(v2[c0], 512.0f, 524288.0f);
  const float C1 = fmaf(v2[c1], 512.0f, 524288.0f);
  unsigned kk1[16], kk2[16];
  #pragma unroll
  for (int i = 0; i < 4; ++i)
    #pragma unroll
    for (int r = 0; r < 4; ++r) {
      const int p = i * 4 + r;
      const unsigned k0 = ((unsigned)fmaf(-1024.0f, acc[i][0][r], C0) << 12) | (unsigned)c0;
      const unsigned k1 = ((unsigned)fmaf(-1024.0f, acc[i][1][r], C1) << 12) | (unsigned)c1;
      kk1[p] = min(k0, k1);
      kk2[p] = max(k0, k1);
    }
  // butterfly top-2 merge across the 16 col-holder lanes (within quad group)
  #pragma unroll
  for (int p = 0; p < 16; ++p) {
    unsigned k1 = kk1[p], k2 = kk2[p];
    #pragma unroll
    for (int mask = 1; mask <= 8; mask <<= 1) {
      const unsigned o1 = (unsigned)__shfl_xor((int)k1, mask);
      const unsigned o2 = (unsigned)__shfl_xor((int)k2, mask);
      k2 = min(min(k2, o2), max(k1, o1));
      k1 = min(k1, o1);
    }
    kk1[p] = k1; kk2[p] = k2;
  }
  if (cl == 0) {
    #pragma unroll
    for (int p = 0; p < 16; ++p) {
      const int rl = (p >> 2) * 16 + q * 4 + (p & 3);
      eK1[rl][wid] = kk1[p]; eK2[rl][wid] = kk2[p];
    }
  }
  __syncthreads();
  if (tid < 64) {
    unsigned K1 = 0xFFFFFFFFu, K2 = 0xFFFFFFFFu;
    #pragma unroll
    for (int w = 0; w < 4; ++w) {
      const unsigned b1 = eK1[tid][w], b2 = eK2[tid][w];
      K2 = min(min(K2, b2), max(K1, b1));
      K1 = min(K1, b1);
    }
    pk1[(size_t)cb * M + row0 + tid] = K1;
    pk2[(size_t)cb * M + row0 + tid] = K2;
  }
}

// ---------------------------------------------------------------------------
// Kernel 4: merge NSPLIT partials -> token; flagged patches emit fp64-rescore
// candidate pairs (second streaming pass, L2-hot). Inits minkey.
// ---------------------------------------------------------------------------
__global__ __launch_bounds__(256) void reduce_gather_kernel(
    const unsigned* __restrict__ pk1, const unsigned* __restrict__ pk2,
    float* __restrict__ tok, unsigned long long* __restrict__ minkey,
    unsigned* __restrict__ pairs, int* __restrict__ paircount) {
  const int m = blockIdx.x * 256 + threadIdx.x;
  unsigned K1 = 0xFFFFFFFFu, K2 = 0xFFFFFFFFu;
  for (int s = 0; s < NSPLIT; ++s) {
    const unsigned b1 = pk1[(size_t)s * M + m];
    const unsigned b2 = pk2[(size_t)s * M + m];
    K2 = min(min(K2, b2), max(K1, b1));
    K1 = min(K1, b1);
  }
  tok[m] = (float)(K1 & 4095u);
  minkey[m] = 0xFFFFFFFFFFFFFFFFull;
  if ((int)(K2 >> 12) - (int)(K1 >> 12) <= QMARGIN) {
    const int th = (int)(K1 >> 12) + QMARGIN;
    int cnt = 0;
    for (int s = 0; s < NSPLIT; ++s) {
      const unsigned b1 = pk1[(size_t)s * M + m];
      const unsigned b2 = pk2[(size_t)s * M + m];
      cnt += ((int)(b2 >> 12) <= th) ? 128
           : (((int)(b1 >> 12) <= th) ? 1 : 0);
    }
    int base = atomicAdd(paircount, cnt);
    if (base + cnt <= PAIR_CAP) {
      const unsigned mh = (unsigned)m << 12;
      for (int s = 0; s < NSPLIT; ++s) {
        const unsigned b1 = pk1[(size_t)s * M + m];
        const unsigned b2 = pk2[(size_t)s * M + m];
        if ((int)(b2 >> 12) <= th) {          // split may hide a 3rd contender
          for (int r = 0; r < 128; ++r) pairs[base + r] = mh | (unsigned)(s * 128 + r);
          base += 128;
        } else if ((int)(b1 >> 12) <= th) {   // only stored winner qualifies
          pairs[base++] = mh | (b1 & 4095u);
        }
      }
    }
  }
}

// ---------------------------------------------------------------------------
// Kernel 5: exact fp64 rescore, one wave per pair, single pass.
// key = (bits(d2) & ~0xFFF) | row: atomicMin = argmin with low-index
// tie-break; 12 dropped mantissa bits = ~1e-9 abs tolerance (safe).
// ---------------------------------------------------------------------------
__global__ __launch_bounds__(256) void refine_score(
    const float* __restrict__ patches, const float* __restrict__ vocab,
    const unsigned* __restrict__ pairs, const int* __restrict__ paircount,
    unsigned long long* __restrict__ minkey) {
  const int lane = threadIdx.x & 63;
  const int gw = (blockIdx.x * 256 + threadIdx.x) >> 6;
  const int nw = (gridDim.x * 256) >> 6;
  int np = *paircount;
  if (np > PAIR_CAP) np = PAIR_CAP;
  for (int i = gw; i < np; i += nw) {
    const unsigned pr = pairs[i];
    const int m = pr >> 12, row = pr & 4095;
    const float4 pv = *(const float4*)(patches + (size_t)m * D + (lane << 2));
    const float4 vv = *(const float4*)(vocab + (size_t)row * D + (lane << 2));
    double acc = 0.0, df;
    df = (double)pv.x - (double)vv.x; acc = fma(df, df, acc);
    df = (double)pv.y - (double)vv.y; acc = fma(df, df, acc);
    df = (double)pv.z - (double)vv.z; acc = fma(df, df, acc);
    df = (double)pv.w - (double)vv.w; acc = fma(df, df, acc);
    #pragma unroll
    for (int off = 32; off > 0; off >>= 1) acc += __shfl_down(acc, off);
    if (lane == 0) {
      const unsigned long long key =
          ((unsigned long long)__double_as_longlong(acc) & ~0xFFFull) | (unsigned)row;
      atomicMin(&minkey[m], key);
    }
  }
}

// ---------------------------------------------------------------------------
// Kernel 6: write refined tokens (grid-stride over pairs; redundant same-value
// writes per flagged patch are benign).
// ---------------------------------------------------------------------------
__global__ __launch_bounds__(256) void refine_final(
    const unsigned* __restrict__ pairs, const int* __restrict__ paircount,
    const unsigned long long* __restrict__ minkey, float* __restrict__ tok) {
  int np = *paircount;
  if (np > PAIR_CAP) np = PAIR_CAP;
  for (int i = blockIdx.x * 256 + threadIdx.x; i < np; i += gridDim.x * 256) {
    const int m = pairs[i] >> 12;
    tok[m] = (float)(unsigned)(minkey[m] & 4095ull);
  }
}

// ---------------------------------------------------------------------------
extern "C" void kernel_launch(void* const* d_in, const int* in_sizes, int n_in,
                              void* d_out, int out_size, void* d_ws, size_t ws_size,
                              hipStream_t stream) {
  const float* images = (const float*)d_in[0];   // [64,256,256]
  const float* vocab  = (const float*)d_in[1];   // [4096,256]
  float* out     = (float*)d_out;
  float* patches = out;            // M*D floats
  float* tokens  = out + (size_t)M * D;

  // workspace layout (bytes):
  // Ah 8MB | Vh 2MB | v2 16KB | pk1 2MB | pk2 2MB | minkey 128KB |
  // paircount 64B | pairs 4MB   (~18.2 MB)
  char* ws = (char*)d_ws;
  _Float16* Ah       = (_Float16*)(ws);
  _Float16* Vh       = (_Float16*)(ws + 8388608);
  float*    v2       = (float*)   (ws + 10485760);
  unsigned* pk1      = (unsigned*)(ws + 10502144);
  unsigned* pk2      = (unsigned*)(ws + 12599296);
  unsigned long long* minkey = (unsigned long long*)(ws + 14696448);
  int*      paircount= (int*)     (ws + 14827520);
  unsigned* pairs    = (unsigned*)(ws + 14827584);

  patchify_half_kernel<<<(M * D / 4) / 256, 256, 0, stream>>>(images, patches, Ah,
                                                              paircount);
  vocab_half_v2_kernel<<<(V * 64) / 256, 256, 0, stream>>>(vocab, Vh, v2);
  gemm_score_kernel<<<dim3(V / 128, M / 64), 256, 0, stream>>>(Ah, Vh, v2, pk1, pk2);
  reduce_gather_kernel<<<M / 256, 256, 0, stream>>>(pk1, pk2, tokens, minkey,
                                                    pairs, paircount);
  refine_score<<<512, 256, 0, stream>>>(patches, vocab, pairs, paircount, minkey);
  refine_final<<<64, 256, 0, stream>>>(pairs, paircount, minkey, tokens);
}

// Round 8
// 172.838 us; speedup vs baseline: 1.6377x; 1.0256x over previous
//
#include <hip/hip_runtime.h>
#include <math.h>

// Problem: images [64,256,256] f32 -> patches [16384][256] f32 (identity perm)
//          tokens [16384] = argmin_v ||patch - vocab[v]||^2, vocab [4096][256] f32
#define PS      16
#define D       256
#define V       4096
#define M       16384
#define NSPLIT  16              // V / 256 column splits
#define PAIR_CAP 1048576
// Scores packed as u32 keys: q = (u32)((s + 1024) * 512)  (20 bits), key =
// (q << 12) | col. min() on keys = argmin with lowest-index tie-break.
// fp16 score-diff error sigma ~3e-2; QMARGIN 130 quanta (=0.254) is ~8 sigma
// incl. trunc slack -> P(true-argmin excluded) negligible. Flagged (~3%)
// get exact fp64 on a candidate set provably containing the argmin.
#define QMARGIN 130

typedef _Float16 half8 __attribute__((ext_vector_type(8)));
typedef _Float16 half4 __attribute__((ext_vector_type(4)));
typedef float    f32x4 __attribute__((ext_vector_type(4)));

__device__ __forceinline__ void gload_lds16(const void* g, void* l) {
  __builtin_amdgcn_global_load_lds(
      (const __attribute__((address_space(1))) unsigned int*)g,
      (__attribute__((address_space(3))) unsigned int*)l, 16, 0, 0);
}

// ---------------------------------------------------------------------------
// Kernel 1: fused prep. Blocks [0,4096): patchify (float4) + fp16 copy.
// Blocks [4096,5120): vocab fp16 copy + v2. Block 0 zeros pair counter.
// ---------------------------------------------------------------------------
__global__ __launch_bounds__(256) void prep_kernel(
    const float* __restrict__ img, const float* __restrict__ vocab,
    float* __restrict__ outp, _Float16* __restrict__ Ah,
    _Float16* __restrict__ Vh, float* __restrict__ v2,
    int* __restrict__ paircount) {
  if (blockIdx.x < 4096) {
    if (blockIdx.x == 0 && threadIdx.x == 0) *paircount = 0;
    const int t  = blockIdx.x * 256 + threadIdx.x;   // M*D/4 threads
    const int o4 = t << 2;
    const int b   = o4 >> 16;
    const int rem = o4 & 65535;
    const int n   = rem >> 8;
    const int d   = rem & 255;
    const int py = n >> 4, px = n & 15, i = d >> 4, j = d & 15;
    const float4 v = *(const float4*)(img + (b << 16) + ((py * PS + i) << 8) + px * PS + j);
    *(float4*)(outp + o4) = v;
    half4 h = { (_Float16)v.x, (_Float16)v.y, (_Float16)v.z, (_Float16)v.w };
    *(half4*)(Ah + o4) = h;
  } else {
    const int gtid = (blockIdx.x - 4096) * 256 + threadIdx.x;
    const int row  = gtid >> 6;
    const int lane = gtid & 63;
    const float4 v = *(const float4*)(vocab + (size_t)row * D + (lane << 2));
    half4 h = { (_Float16)v.x, (_Float16)v.y, (_Float16)v.z, (_Float16)v.w };
    *(half4*)(Vh + (size_t)row * D + (lane << 2)) = h;
    float s = v.x * v.x + v.y * v.y + v.z * v.z + v.w * v.w;
    #pragma unroll
    for (int off = 32; off > 0; off >>= 1) s += __shfl_down(s, off);
    if (lane == 0) v2[row] = s;
  }
}

// ---------------------------------------------------------------------------
// Kernel 2: fp16 MFMA score GEMM, spill-free by construction.
// Block = 64 rows x 256 cols; wave = 64 rows x 64 cols (acc[4][4], 128 MFMA)
// so the fixed per-block epilogue (butterfly) amortizes over 2x the MFMA of
// R7. A tile (64x256, 32KB) LDS-resident via swizzled global_load_lds, ONE
// barrier. B fragments direct global->VGPR (16B/lane, Vh 2MB L2-resident).
// kt loop NOT unrolled (#pragma unroll 1) -- R6's spill lesson.
// ---------------------------------------------------------------------------
__global__ __launch_bounds__(256, 3) void gemm_score_kernel(
    const _Float16* __restrict__ Ah,   // [M][256]
    const _Float16* __restrict__ Vh,   // [V][256]
    const float* __restrict__ v2,
    unsigned* __restrict__ pk1, unsigned* __restrict__ pk2) {
  __shared__ __align__(16) _Float16 Af[8 * 64 * 32];  // [kt][row][32] = 32 KB
  __shared__ unsigned eK1[64][4];
  __shared__ unsigned eK2[64][4];

  const int tid  = threadIdx.x;
  const int lane = tid & 63;
  const int wid  = tid >> 6;
  const int row0 = blockIdx.x * 64;
  const int sp   = blockIdx.y;              // col split 0..15
  const int col0 = sp * 256 + wid * 64;     // this wave's 64 cols

  // ---- stage A tile once (8 gloads/wave, one barrier) ----
  // global addr carries the XOR swizzle; HW writes LDS at base + lane*16,
  // so LDS granule p of row r holds global granule p ^ ((r>>1)&3).
  {
    const int srow = lane >> 2;
    const int sg   = ((lane & 3) ^ ((srow >> 1) & 3)) << 3;   // halves
    const _Float16* Ag = Ah + (size_t)(row0 + wid * 16 + srow) * D + sg;
    _Float16* Al = Af + wid * 16 * 32;
    #pragma unroll
    for (int kt = 0; kt < 8; ++kt)
      gload_lds16(Ag + kt * 32, Al + kt * 64 * 32);
  }
  __syncthreads();

  const int cl = lane & 15;           // fragment row/col within 16
  const int q  = lane >> 4;           // quad: k-chunk selector
  const int fg = (q ^ ((cl >> 1) & 3)) << 3;           // de-swizzle granule
  const _Float16* Ab = Af + cl * 32 + fg;

  const _Float16* Bp = Vh + (size_t)(col0 + cl) * D + q * 8;  // + j*16*D + kt*32

  f32x4 acc[4][4];
  #pragma unroll
  for (int i = 0; i < 4; ++i)
    #pragma unroll
    for (int j = 0; j < 4; ++j) acc[i][j] = (f32x4){0.f, 0.f, 0.f, 0.f};

  #pragma unroll 1                    // keep live set bounded (R6 lesson)
  for (int kt = 0; kt < 8; ++kt) {
    half8 b[4];
    #pragma unroll
    for (int j = 0; j < 4; ++j)
      b[j] = *(const half8*)(Bp + (size_t)j * 16 * D + kt * 32);
    half8 af[4];
    #pragma unroll
    for (int i = 0; i < 4; ++i)
      af[i] = *(const half8*)(Ab + kt * 2048 + i * 512);
    #pragma unroll
    for (int i = 0; i < 4; ++i)
      #pragma unroll
      for (int j = 0; j < 4; ++j)
        acc[i][j] = __builtin_amdgcn_mfma_f32_16x16x32_f16(af[i], b[j], acc[i][j], 0, 0, 0);
  }

  // Epilogue. C/D layout: col=lane&15, row=quad*4+reg (m89/m91-verified).
  // key_f = (score+1024)*512 = (v2+1024)*512 - 1024*acc
  float Cj[4];
  #pragma unroll
  for (int j = 0; j < 4; ++j) Cj[j] = fmaf(v2[col0 + j * 16 + cl], 512.0f, 524288.0f);
  unsigned kk1[16], kk2[16];
  #pragma unroll
  for (int i = 0; i < 4; ++i)
    #pragma unroll
    for (int r = 0; r < 4; ++r) {
      const int p = i * 4 + r;
      unsigned K1 = 0xFFFFFFFFu, K2 = 0xFFFFFFFFu;
      #pragma unroll
      for (int j = 0; j < 4; ++j) {
        const unsigned key =
            ((unsigned)fmaf(-1024.0f, acc[i][j][r], Cj[j]) << 12) |
            (unsigned)(col0 + j * 16 + cl);
        K2 = min(K2, max(K1, key));
        K1 = min(K1, key);
      }
      kk1[p] = K1; kk2[p] = K2;
    }
  // butterfly top-2 merge across the 16 col-holder lanes (within quad group)
  #pragma unroll
  for (int p = 0; p < 16; ++p) {
    unsigned k1 = kk1[p], k2 = kk2[p];
    #pragma unroll
    for (int mask = 1; mask <= 8; mask <<= 1) {
      const unsigned o1 = (unsigned)__shfl_xor((int)k1, mask);
      const unsigned o2 = (unsigned)__shfl_xor((int)k2, mask);
      k2 = min(min(k2, o2), max(k1, o1));
      k1 = min(k1, o1);
    }
    kk1[p] = k1; kk2[p] = k2;
  }
  if (cl == 0) {
    #pragma unroll
    for (int p = 0; p < 16; ++p) {
      const int rl = (p >> 2) * 16 + q * 4 + (p & 3);
      eK1[rl][wid] = kk1[p]; eK2[rl][wid] = kk2[p];
    }
  }
  __syncthreads();
  if (tid < 64) {
    unsigned K1 = 0xFFFFFFFFu, K2 = 0xFFFFFFFFu;
    #pragma unroll
    for (int w = 0; w < 4; ++w) {
      const unsigned b1 = eK1[tid][w], b2 = eK2[tid][w];
      K2 = min(min(K2, b2), max(K1, b1));
      K1 = min(K1, b1);
    }
    pk1[(size_t)sp * M + row0 + tid] = K1;
    pk2[(size_t)sp * M + row0 + tid] = K2;
  }
}

// ---------------------------------------------------------------------------
// Kernel 3: merge NSPLIT partials -> token; flagged patches emit fp64-rescore
// candidate pairs (second streaming pass, L2-hot). Inits minkey.
// ---------------------------------------------------------------------------
__global__ __launch_bounds__(256) void reduce_gather_kernel(
    const unsigned* __restrict__ pk1, const unsigned* __restrict__ pk2,
    float* __restrict__ tok, unsigned long long* __restrict__ minkey,
    unsigned* __restrict__ pairs, int* __restrict__ paircount) {
  const int m = blockIdx.x * 256 + threadIdx.x;
  unsigned K1 = 0xFFFFFFFFu, K2 = 0xFFFFFFFFu;
  for (int s = 0; s < NSPLIT; ++s) {
    const unsigned b1 = pk1[(size_t)s * M + m];
    const unsigned b2 = pk2[(size_t)s * M + m];
    K2 = min(min(K2, b2), max(K1, b1));
    K1 = min(K1, b1);
  }
  tok[m] = (float)(K1 & 4095u);
  minkey[m] = 0xFFFFFFFFFFFFFFFFull;
  if ((int)(K2 >> 12) - (int)(K1 >> 12) <= QMARGIN) {
    const int th = (int)(K1 >> 12) + QMARGIN;
    int cnt = 0;
    for (int s = 0; s < NSPLIT; ++s) {
      const unsigned b1 = pk1[(size_t)s * M + m];
      const unsigned b2 = pk2[(size_t)s * M + m];
      cnt += ((int)(b2 >> 12) <= th) ? 256
           : (((int)(b1 >> 12) <= th) ? 1 : 0);
    }
    int base = atomicAdd(paircount, cnt);
    if (base + cnt <= PAIR_CAP) {
      const unsigned mh = (unsigned)m << 12;
      for (int s = 0; s < NSPLIT; ++s) {
        const unsigned b1 = pk1[(size_t)s * M + m];
        const unsigned b2 = pk2[(size_t)s * M + m];
        if ((int)(b2 >> 12) <= th) {          // split may hide a 3rd contender
          for (int r = 0; r < 256; ++r) pairs[base + r] = mh | (unsigned)(s * 256 + r);
          base += 256;
        } else if ((int)(b1 >> 12) <= th) {   // only stored winner qualifies
          pairs[base++] = mh | (b1 & 4095u);
        }
      }
    }
  }
}

// ---------------------------------------------------------------------------
// Kernel 4: exact fp64 rescore, one wave per pair, single pass.
// key = (bits(d2) & ~0xFFF) | row: atomicMin = argmin with low-index
// tie-break; 12 dropped mantissa bits = ~1e-9 abs tolerance (safe).
// ---------------------------------------------------------------------------
__global__ __launch_bounds__(256) void refine_score(
    const float* __restrict__ patches, const float* __restrict__ vocab,
    const unsigned* __restrict__ pairs, const int* __restrict__ paircount,
    unsigned long long* __restrict__ minkey) {
  const int lane = threadIdx.x & 63;
  const int gw = (blockIdx.x * 256 + threadIdx.x) >> 6;
  const int nw = (gridDim.x * 256) >> 6;
  int np = *paircount;
  if (np > PAIR_CAP) np = PAIR_CAP;
  for (int i = gw; i < np; i += nw) {
    const unsigned pr = pairs[i];
    const int m = pr >> 12, row = pr & 4095;
    const float4 pv = *(const float4*)(patches + (size_t)m * D + (lane << 2));
    const float4 vv = *(const float4*)(vocab + (size_t)row * D + (lane << 2));
    double acc = 0.0, df;
    df = (double)pv.x - (double)vv.x; acc = fma(df, df, acc);
    df = (double)pv.y - (double)vv.y; acc = fma(df, df, acc);
    df = (double)pv.z - (double)vv.z; acc = fma(df, df, acc);
    df = (double)pv.w - (double)vv.w; acc = fma(df, df, acc);
    #pragma unroll
    for (int off = 32; off > 0; off >>= 1) acc += __shfl_down(acc, off);
    if (lane == 0) {
      const unsigned long long key =
          ((unsigned long long)__double_as_longlong(acc) & ~0xFFFull) | (unsigned)row;
      atomicMin(&minkey[m], key);
    }
  }
}

// ---------------------------------------------------------------------------
// Kernel 5: write refined tokens (grid-stride over pairs; redundant same-value
// writes per flagged patch are benign).
// ---------------------------------------------------------------------------
__global__ __launch_bounds__(256) void refine_final(
    const unsigned* __restrict__ pairs, const int* __restrict__ paircount,
    const unsigned long long* __restrict__ minkey, float* __restrict__ tok) {
  int np = *paircount;
  if (np > PAIR_CAP) np = PAIR_CAP;
  for (int i = blockIdx.x * 256 + threadIdx.x; i < np; i += gridDim.x * 256) {
    const int m = pairs[i] >> 12;
    tok[m] = (float)(unsigned)(minkey[m] & 4095ull);
  }
}

// ---------------------------------------------------------------------------
extern "C" void kernel_launch(void* const* d_in, const int* in_sizes, int n_in,
                              void* d_out, int out_size, void* d_ws, size_t ws_size,
                              hipStream_t stream) {
  const float* images = (const float*)d_in[0];   // [64,256,256]
  const float* vocab  = (const float*)d_in[1];   // [4096,256]
  float* out     = (float*)d_out;
  float* patches = out;            // M*D floats
  float* tokens  = out + (size_t)M * D;

  // workspace layout (bytes):
  // Ah 8MB | Vh 2MB | v2 16KB | pk1 1MB | pk2 1MB | minkey 128KB |
  // paircount 64B | pairs 4MB   (~16.2 MB)
  char* ws = (char*)d_ws;
  _Float16* Ah       = (_Float16*)(ws);
  _Float16* Vh       = (_Float16*)(ws + 8388608);
  float*    v2       = (float*)   (ws + 10485760);
  unsigned* pk1      = (unsigned*)(ws + 10502144);
  unsigned* pk2      = (unsigned*)(ws + 11550720);
  unsigned long long* minkey = (unsigned long long*)(ws + 12599296);
  int*      paircount= (int*)     (ws + 12730368);
  unsigned* pairs    = (unsigned*)(ws + 12730432);

  prep_kernel<<<4096 + 1024, 256, 0, stream>>>(images, vocab, patches, Ah,
                                               Vh, v2, paircount);
  gemm_score_kernel<<<dim3(M / 64, NSPLIT), 256, 0, stream>>>(Ah, Vh, v2, pk1, pk2);
  reduce_gather_kernel<<<M / 256, 256, 0, stream>>>(pk1, pk2, tokens, minkey,
                                                    pairs, paircount);
  refine_score<<<512, 256, 0, stream>>>(patches, vocab, pairs, paircount, minkey);
  refine_final<<<64, 256, 0, stream>>>(pairs, paircount, minkey, tokens);
}